// Round 19
// baseline (167.400 us; speedup 1.0000x reference)
//
#include <hip/hip_runtime.h>
#include <hip/hip_fp16.h>

#define FEAT1 64
#define FEAT2 16
#define NCHUNK_R 800   // radix chunks (chunkE = 1000 edges)
#define FCAP 4096      // LDS cache capacity for fine_both dst bucket

typedef _Float16 f16x8 __attribute__((ext_vector_type(8)));
typedef _Float16 f16x4 __attribute__((ext_vector_type(4)));
typedef float f32x4 __attribute__((ext_vector_type(4)));
typedef float f32x2 __attribute__((ext_vector_type(2)));

#define DPP_ADD(x, ctrl) \
    ((x) + __int_as_float(__builtin_amdgcn_update_dpp(0, __float_as_int(x), (ctrl), 0xf, 0xf, true)))

// ---------------- radix sort pipeline ----------------

__global__ __launch_bounds__(256) void coarse_hist(const int* __restrict__ src,
                                                   const int* __restrict__ dst,
                                                   int* __restrict__ partS, int* __restrict__ partD,
                                                   int E, int chunkE) {
    __shared__ int hS[256], hD[256];
    int tid = threadIdx.x, chunk = blockIdx.x;
    hS[tid] = 0; hD[tid] = 0;
    __syncthreads();
    int e0 = chunk * chunkE;
    int nq = chunkE >> 2;
    if (tid < nq) {
        int e = e0 + tid * 4;
        if (e + 3 < E) {
            int4 s4 = *(const int4*)(src + e);
            int4 d4 = *(const int4*)(dst + e);
            atomicAdd(&hS[s4.x >> 8], 1); atomicAdd(&hS[s4.y >> 8], 1);
            atomicAdd(&hS[s4.z >> 8], 1); atomicAdd(&hS[s4.w >> 8], 1);
            atomicAdd(&hD[d4.x >> 8], 1); atomicAdd(&hD[d4.y >> 8], 1);
            atomicAdd(&hD[d4.z >> 8], 1); atomicAdd(&hD[d4.w >> 8], 1);
        } else {
            for (int k = 0; k < 4 && e + k < E; k++) {
                atomicAdd(&hS[src[e + k] >> 8], 1);
                atomicAdd(&hD[dst[e + k] >> 8], 1);
            }
        }
    }
    __syncthreads();
    partS[chunk * 256 + tid] = hS[tid];
    partD[chunk * 256 + tid] = hD[tid];
}

__global__ __launch_bounds__(256) void scan_chunks(int* partS, int* partD,
                                                   int* totS, int* totD, int nchunk) {
    __shared__ int sums[256];
    int tid = threadIdx.x;
    int bin = blockIdx.x & 255;
    int* part = (blockIdx.x >> 8) ? partD : partS;
    int* tot  = (blockIdx.x >> 8) ? totD : totS;
    int v[4];
    int base = tid * 4, local = 0;
#pragma unroll
    for (int j = 0; j < 4; j++) {
        int c = base + j;
        v[j] = (c < nchunk) ? part[c * 256 + bin] : 0;
        local += v[j];
    }
    sums[tid] = local;
    __syncthreads();
    for (int off = 1; off < 256; off <<= 1) {
        int t = (tid >= off) ? sums[tid - off] : 0;
        __syncthreads();
        sums[tid] += t;
        __syncthreads();
    }
    int run = sums[tid] - local;
#pragma unroll
    for (int j = 0; j < 4; j++) {
        int c = base + j;
        if (c < nchunk) part[c * 256 + bin] = run;
        run += v[j];
    }
    if (tid == 255) tot[bin] = run;
}

__global__ __launch_bounds__(256) void partition_coarse(const int* __restrict__ src,
                                                        const int* __restrict__ dst,
                                                        const int* __restrict__ partS,
                                                        const int* __restrict__ partD,
                                                        const int* __restrict__ totS,
                                                        const int* __restrict__ totD,
                                                        unsigned int* __restrict__ packD,
                                                        unsigned char* __restrict__ srcLow,
                                                        int E, int chunkE) {
    __shared__ int curS[256], curD[256], sc[256];
    int tid = threadIdx.x, chunk = blockIdx.x;
    int v = totS[tid];
    sc[tid] = v;
    __syncthreads();
    for (int off = 1; off < 256; off <<= 1) {
        int t = (tid >= off) ? sc[tid - off] : 0;
        __syncthreads();
        sc[tid] += t;
        __syncthreads();
    }
    curS[tid] = (sc[tid] - v) + partS[chunk * 256 + tid];
    __syncthreads();
    v = totD[tid];
    sc[tid] = v;
    __syncthreads();
    for (int off = 1; off < 256; off <<= 1) {
        int t = (tid >= off) ? sc[tid - off] : 0;
        __syncthreads();
        sc[tid] += t;
        __syncthreads();
    }
    curD[tid] = (sc[tid] - v) + partD[chunk * 256 + tid];
    __syncthreads();
    int e0 = chunk * chunkE;
    int nq = chunkE >> 2;
    if (tid < nq) {
        int e = e0 + tid * 4;
        if (e + 3 < E) {
            int4 s4 = *(const int4*)(src + e);
            int4 d4 = *(const int4*)(dst + e);
            int ss[4] = {s4.x, s4.y, s4.z, s4.w};
            int dd[4] = {d4.x, d4.y, d4.z, d4.w};
#pragma unroll
            for (int k = 0; k < 4; k++) {
                int pD = atomicAdd(&curD[dd[k] >> 8], 1);
                packD[pD] = ((unsigned)(dd[k] & 255) << 16) | (unsigned)ss[k];
                int pS = atomicAdd(&curS[ss[k] >> 8], 1);
                srcLow[pS] = (unsigned char)(ss[k] & 255);
            }
        } else {
            for (int k = 0; k < 4 && e + k < E; k++) {
                int s = src[e + k], d = dst[e + k];
                int pD = atomicAdd(&curD[d >> 8], 1);
                packD[pD] = ((unsigned)(d & 255) << 16) | (unsigned)s;
                int pS = atomicAdd(&curS[s >> 8], 1);
                srcLow[pS] = (unsigned char)(s & 255);
            }
        }
    }
}

__global__ __launch_bounds__(256) void fine_both(const unsigned int* __restrict__ packD,
                                                 const int* __restrict__ totD,
                                                 unsigned short* __restrict__ sorted_src,
                                                 int2* __restrict__ oc,
                                                 float* __restrict__ norm_dst,
                                                 const unsigned char* __restrict__ srcLow,
                                                 const int* __restrict__ totS,
                                                 float* __restrict__ norm_src, int N) {
    __shared__ int hist[256], pfx[256], cur[256];
    __shared__ unsigned int ecache[FCAP];
    int tid = threadIdx.x;
    if (blockIdx.x < 256) {
        int b = blockIdx.x;
        int tv = totD[tid];
        pfx[tid] = tv;
        __syncthreads();
        for (int off = 1; off < 256; off <<= 1) {
            int t = (tid >= off) ? pfx[tid - off] : 0;
            __syncthreads();
            pfx[tid] += t;
            __syncthreads();
        }
        int lo = pfx[b] - totD[b];
        int n = totD[b];
        __syncthreads();
        hist[tid] = 0;
        for (int i = tid; i < n; i += 256) {
            unsigned p = packD[lo + i];
            if (i < FCAP) ecache[i] = p;
            atomicAdd(&hist[p >> 16], 1);
        }
        __syncthreads();
        int v = hist[tid];
        pfx[tid] = v;
        __syncthreads();
        for (int off = 1; off < 256; off <<= 1) {
            int t = (tid >= off) ? pfx[tid - off] : 0;
            __syncthreads();
            pfx[tid] += t;
            __syncthreads();
        }
        int my = pfx[tid] - v;
        cur[tid] = lo + my;
        int node = b * 256 + tid;
        if (node < N) {
            oc[node] = make_int2(lo + my, v);
            norm_dst[node] = rsqrtf(fmaxf((float)v, 1.0f));
        }
        __syncthreads();
        for (int i = tid; i < n; i += 256) {
            unsigned p = (i < FCAP) ? ecache[i] : packD[lo + i];
            int pos = atomicAdd(&cur[p >> 16], 1);
            sorted_src[pos] = (unsigned short)(p & 0xFFFFu);
        }
    } else {
        int b = blockIdx.x - 256;
        int tv = totS[tid];
        pfx[tid] = tv;
        __syncthreads();
        for (int off = 1; off < 256; off <<= 1) {
            int t = (tid >= off) ? pfx[tid - off] : 0;
            __syncthreads();
            pfx[tid] += t;
            __syncthreads();
        }
        int lo = pfx[b] - totS[b];
        int n = totS[b];
        __syncthreads();
        hist[tid] = 0;
        __syncthreads();
        for (int i = lo + tid; i < lo + n; i += 256) atomicAdd(&hist[srcLow[i]], 1);
        __syncthreads();
        int node = b * 256 + tid;
        if (node < N) norm_src[node] = rsqrtf(fmaxf((float)hist[tid], 1.0f));
    }
}

// ---------------- MFMA GEMM layer 1 -> fp8 h1 ----------------

__global__ __launch_bounds__(256) void gemm1_kernel(const float* __restrict__ X,
                                                    const float* __restrict__ W1,
                                                    const float* __restrict__ norm_src,
                                                    unsigned char* __restrict__ h1, int N) {
    __shared__ _Float16 sWt[64 * 72];
    __shared__ float snorm[128];
    __shared__ _Float16 sTile[4][16 * 72];
    int tid = threadIdx.x;
    int row_blk = blockIdx.x * 128;
    for (int i = tid; i < 4096; i += 256) {
        int k = i >> 6, n = i & 63;
        sWt[n * 72 + k] = (_Float16)W1[i];
    }
    if (tid < 128) {
        int r = row_blk + tid;
        snorm[tid] = (r < N) ? norm_src[r] : 0.f;
    }
    __syncthreads();
    int wave = tid >> 6, lane = tid & 63;
    int m = lane & 15, quad = lane >> 4;
    f16x8 bfrag[4][2];
#pragma unroll
    for (int nt = 0; nt < 4; nt++)
#pragma unroll
        for (int kit = 0; kit < 2; kit++)
            bfrag[nt][kit] = *(const f16x8*)&sWt[(nt * 16 + m) * 72 + kit * 32 + quad * 8];
    _Float16* tile = sTile[wave];
#pragma unroll
    for (int t = 0; t < 2; t++) {
        int row0 = row_blk + wave * 32 + t * 16;
        int row = row0 + m;
        bool inb = row < N;
        f32x4 acc[4] = {{0.f,0.f,0.f,0.f},{0.f,0.f,0.f,0.f},{0.f,0.f,0.f,0.f},{0.f,0.f,0.f,0.f}};
#pragma unroll
        for (int kit = 0; kit < 2; kit++) {
            f16x8 afrag;
            if (inb) {
                const float4* xp = (const float4*)(X + (size_t)row * 64 + kit * 32 + quad * 8);
                float4 x0 = xp[0], x1 = xp[1];
                afrag[0] = (_Float16)x0.x; afrag[1] = (_Float16)x0.y;
                afrag[2] = (_Float16)x0.z; afrag[3] = (_Float16)x0.w;
                afrag[4] = (_Float16)x1.x; afrag[5] = (_Float16)x1.y;
                afrag[6] = (_Float16)x1.z; afrag[7] = (_Float16)x1.w;
            } else {
#pragma unroll
                for (int j = 0; j < 8; j++) afrag[j] = (_Float16)0.f;
            }
#pragma unroll
            for (int nt = 0; nt < 4; nt++)
                acc[nt] = __builtin_amdgcn_mfma_f32_16x16x32_f16(afrag, bfrag[nt][kit], acc[nt], 0, 0, 0);
        }
#pragma unroll
        for (int reg = 0; reg < 4; reg++) {
            int r = quad * 4 + reg;
            float nrm = snorm[wave * 32 + t * 16 + r];
#pragma unroll
            for (int nt = 0; nt < 4; nt++)
                tile[r * 72 + nt * 16 + m] = (_Float16)(acc[nt][reg] * nrm);
        }
        __syncthreads();
        int rr = lane >> 2, g = lane & 3;
        f16x8 p0 = *(const f16x8*)&tile[rr * 72 + g * 16];
        f16x8 p1 = *(const f16x8*)&tile[rr * 72 + g * 16 + 8];
        int orow = row0 + rr;
        if (orow < N) {
            int a, b;
            uint4 wv;
            a = __builtin_amdgcn_cvt_pk_fp8_f32((float)p0[0], (float)p0[1], 0, false);
            b = __builtin_amdgcn_cvt_pk_fp8_f32((float)p0[2], (float)p0[3], a, true);
            wv.x = (unsigned)b;
            a = __builtin_amdgcn_cvt_pk_fp8_f32((float)p0[4], (float)p0[5], 0, false);
            b = __builtin_amdgcn_cvt_pk_fp8_f32((float)p0[6], (float)p0[7], a, true);
            wv.y = (unsigned)b;
            a = __builtin_amdgcn_cvt_pk_fp8_f32((float)p1[0], (float)p1[1], 0, false);
            b = __builtin_amdgcn_cvt_pk_fp8_f32((float)p1[2], (float)p1[3], a, true);
            wv.z = (unsigned)b;
            a = __builtin_amdgcn_cvt_pk_fp8_f32((float)p1[4], (float)p1[5], 0, false);
            b = __builtin_amdgcn_cvt_pk_fp8_f32((float)p1[6], (float)p1[7], a, true);
            wv.w = (unsigned)b;
            *(uint4*)(h1 + (size_t)orow * 64 + g * 16) = wv;
        }
        __syncthreads();
    }
}

// ---------------- fused agg1: 2-row interleaved gather (MLP x2) ----------------

__global__ __launch_bounds__(256) void agg1_fused(const unsigned char* __restrict__ h1,
                                                  const unsigned short* __restrict__ sorted_src,
                                                  const int2* __restrict__ oc,
                                                  const float* __restrict__ norm_dst,
                                                  const float* __restrict__ norm_src,
                                                  const float* __restrict__ b1,
                                                  const float* __restrict__ W2,
                                                  __half* __restrict__ h2, int N, int nwaves) {
    int tid = threadIdx.x;
    int wave = tid >> 6, lane = tid & 63;
    int e_off = lane >> 3;   // 0..7
    int fg = lane & 7;       // feats 8fg..8fg+7
    float w2r[8][2], b1r[8];
#pragma unroll
    for (int k = 0; k < 8; k++) {
        float2 t = *(const float2*)(W2 + (size_t)(fg * 8 + k) * 16 + 2 * e_off);
        w2r[k][0] = t.x; w2r[k][1] = t.y;
        b1r[k] = b1[fg * 8 + k];
    }
    for (int rowA = blockIdx.x * 4 + wave; rowA < N; rowA += 2 * nwaves) {
        int rowB = rowA + nwaves;
        bool hasB = rowB < N;
        int2 scA = oc[rowA];
        int2 scB = hasB ? oc[rowB] : make_int2(0, 0);
        int cA = scA.y, cB = scB.y;
        float ndA = norm_dst[rowA];
        float ndB = hasB ? norm_dst[rowB] : 0.f;
        f32x2 aA[4] = {{0.f,0.f},{0.f,0.f},{0.f,0.f},{0.f,0.f}};
        f32x2 aB[4] = {{0.f,0.f},{0.f,0.f},{0.f,0.f},{0.f,0.f}};
        int cMax = cA > cB ? cA : cB;
        for (int j = 0; j < cMax; j += 8) {
            int je = j + e_off;
            if (je < cA) {
                int s = sorted_src[scA.x + je];
                uint2 wv = *(const uint2*)(h1 + (size_t)s * 64 + fg * 8);
                aA[0] += __builtin_amdgcn_cvt_pk_f32_fp8((int)wv.x, false);
                aA[1] += __builtin_amdgcn_cvt_pk_f32_fp8((int)wv.x, true);
                aA[2] += __builtin_amdgcn_cvt_pk_f32_fp8((int)wv.y, false);
                aA[3] += __builtin_amdgcn_cvt_pk_f32_fp8((int)wv.y, true);
            }
            if (je < cB) {
                int s = sorted_src[scB.x + je];
                uint2 wv = *(const uint2*)(h1 + (size_t)s * 64 + fg * 8);
                aB[0] += __builtin_amdgcn_cvt_pk_f32_fp8((int)wv.x, false);
                aB[1] += __builtin_amdgcn_cvt_pk_f32_fp8((int)wv.x, true);
                aB[2] += __builtin_amdgcn_cvt_pk_f32_fp8((int)wv.y, false);
                aB[3] += __builtin_amdgcn_cvt_pk_f32_fp8((int)wv.y, true);
            }
        }
        float accA[8] = {aA[0][0], aA[0][1], aA[1][0], aA[1][1],
                         aA[2][0], aA[2][1], aA[3][0], aA[3][1]};
        float accB[8] = {aB[0][0], aB[0][1], aB[1][0], aB[1][1],
                         aB[2][0], aB[2][1], aB[3][0], aB[3][1]};
#pragma unroll
        for (int k = 0; k < 8; k++) {
            accA[k] = DPP_ADD(accA[k], 0x128);  // xor8
            accB[k] = DPP_ADD(accB[k], 0x128);
        }
#pragma unroll
        for (int m = 16; m <= 32; m <<= 1)
#pragma unroll
            for (int k = 0; k < 8; k++) {
                accA[k] += __shfl_xor(accA[k], m);
                accB[k] += __shfl_xor(accB[k], m);
            }
        float p0A = 0.f, p1A = 0.f, p0B = 0.f, p1B = 0.f;
#pragma unroll
        for (int k = 0; k < 8; k++) {
            float tA = fmaxf(accA[k] * ndA + b1r[k], 0.f);
            float tB = fmaxf(accB[k] * ndB + b1r[k], 0.f);
            p0A += tA * w2r[k][0];
            p1A += tA * w2r[k][1];
            p0B += tB * w2r[k][0];
            p1B += tB * w2r[k][1];
        }
        p0A = DPP_ADD(p0A, 0xB1); p1A = DPP_ADD(p1A, 0xB1);
        p0B = DPP_ADD(p0B, 0xB1); p1B = DPP_ADD(p1B, 0xB1);
        p0A = DPP_ADD(p0A, 0x4E); p1A = DPP_ADD(p1A, 0x4E);
        p0B = DPP_ADD(p0B, 0x4E); p1B = DPP_ADD(p1B, 0x4E);
        p0A += __shfl_xor(p0A, 4); p1A += __shfl_xor(p1A, 4);
        p0B += __shfl_xor(p0B, 4); p1B += __shfl_xor(p1B, 4);
        if (fg == 0) {
            float nsA = norm_src[rowA];
            ((__half2*)((_Float16*)h2 + (size_t)rowA * 16))[e_off] =
                __floats2half2_rn(p0A * nsA, p1A * nsA);
            if (hasB) {
                float nsB = norm_src[rowB];
                ((__half2*)((_Float16*)h2 + (size_t)rowB * 16))[e_off] =
                    __floats2half2_rn(p0B * nsB, p1B * nsB);
            }
        }
    }
}

// ---------------- layer-2 aggregation: 2-row interleaved ----------------

__global__ __launch_bounds__(256) void agg2_kernel(const __half* __restrict__ h2,
                                                   const unsigned short* __restrict__ sorted_src,
                                                   const int2* __restrict__ oc,
                                                   const float* __restrict__ norm_dst,
                                                   const float* __restrict__ b2,
                                                   float* __restrict__ out, int N, int nwaves) {
    int tid = threadIdx.x;
    int wave = tid >> 6, lane = tid & 63;
    int e_off = lane >> 2;   // 0..15
    int fg = lane & 3;       // feats 4fg..4fg+3
    float b2r[4];
#pragma unroll
    for (int k = 0; k < 4; k++) b2r[k] = b2[fg * 4 + k];
    const _Float16* h2p = (const _Float16*)h2;
    for (int rowA = blockIdx.x * 4 + wave; rowA < N; rowA += 2 * nwaves) {
        int rowB = rowA + nwaves;
        bool hasB = rowB < N;
        int2 scA = oc[rowA];
        int2 scB = hasB ? oc[rowB] : make_int2(0, 0);
        int cA = scA.y, cB = scB.y;
        f32x2 aA[2] = {{0.f,0.f},{0.f,0.f}};
        f32x2 aB[2] = {{0.f,0.f},{0.f,0.f}};
        int cMax = cA > cB ? cA : cB;
        for (int j = 0; j < cMax; j += 16) {
            int je = j + e_off;
            if (je < cA) {
                int s = sorted_src[scA.x + je];
                f16x4 v = *(const f16x4*)(h2p + (size_t)s * 16 + fg * 4);
                f32x2 f0 = {(float)v[0], (float)v[1]};
                f32x2 f1 = {(float)v[2], (float)v[3]};
                aA[0] += f0; aA[1] += f1;
            }
            if (je < cB) {
                int s = sorted_src[scB.x + je];
                f16x4 v = *(const f16x4*)(h2p + (size_t)s * 16 + fg * 4);
                f32x2 f0 = {(float)v[0], (float)v[1]};
                f32x2 f1 = {(float)v[2], (float)v[3]};
                aB[0] += f0; aB[1] += f1;
            }
        }
        float accA[4] = {aA[0][0], aA[0][1], aA[1][0], aA[1][1]};
        float accB[4] = {aB[0][0], aB[0][1], aB[1][0], aB[1][1]};
#pragma unroll
        for (int k = 0; k < 4; k++) {
            accA[k] += __shfl_xor(accA[k], 4);
            accB[k] += __shfl_xor(accB[k], 4);
        }
#pragma unroll
        for (int k = 0; k < 4; k++) {
            accA[k] = DPP_ADD(accA[k], 0x128);  // xor8
            accB[k] = DPP_ADD(accB[k], 0x128);
        }
#pragma unroll
        for (int m = 16; m <= 32; m <<= 1)
#pragma unroll
            for (int k = 0; k < 4; k++) {
                accA[k] += __shfl_xor(accA[k], m);
                accB[k] += __shfl_xor(accB[k], m);
            }
        if (e_off == 0) {
            float ndA = norm_dst[rowA];
            float4 o;
            o.x = accA[0] * ndA + b2r[0];
            o.y = accA[1] * ndA + b2r[1];
            o.z = accA[2] * ndA + b2r[2];
            o.w = accA[3] * ndA + b2r[3];
            ((float4*)(out + (size_t)rowA * 16))[fg] = o;
            if (hasB) {
                float ndB = norm_dst[rowB];
                float4 ob;
                ob.x = accB[0] * ndB + b2r[0];
                ob.y = accB[1] * ndB + b2r[1];
                ob.z = accB[2] * ndB + b2r[2];
                ob.w = accB[3] * ndB + b2r[3];
                ((float4*)(out + (size_t)rowB * 16))[fg] = ob;
            }
        }
    }
}

extern "C" void kernel_launch(void* const* d_in, const int* in_sizes, int n_in,
                              void* d_out, int out_size, void* d_ws, size_t ws_size,
                              hipStream_t stream) {
    const float* X  = (const float*)d_in[0];
    const int* src  = (const int*)d_in[1];
    const int* dst  = (const int*)d_in[2];
    const float* W1 = (const float*)d_in[3];
    const float* b1 = (const float*)d_in[4];
    const float* W2 = (const float*)d_in[5];
    const float* b2 = (const float*)d_in[6];
    float* out = (float*)d_out;

    const int N = in_sizes[0] / FEAT1;  // 50000
    const int E = in_sizes[1];          // 800000
    const int chunkE = (E + NCHUNK_R - 1) / NCHUNK_R;  // 1000

    char* w = (char*)d_ws;
    int* partS = (int*)w;        w += (size_t)NCHUNK_R * 256 * 4;
    int* partD = (int*)w;        w += (size_t)NCHUNK_R * 256 * 4;
    int* totS  = (int*)w;        w += 256 * 4;
    int* totD  = (int*)w;        w += 256 * 4;
    unsigned int* packD = (unsigned int*)w; w += (size_t)E * 4;
    unsigned short* sorted_src = (unsigned short*)w; w += (size_t)E * 2;
    w = (char*)(((size_t)w + 7) & ~(size_t)7);
    int2* oc = (int2*)w;         w += (size_t)N * 8;
    float* norm_src = (float*)w; w += (size_t)N * 4;
    float* norm_dst = (float*)w; w += (size_t)N * 4;
    unsigned char* h1 = (unsigned char*)w; w += (size_t)N * 64;
    __half* h2 = (__half*)w;     w += (size_t)N * 16 * 2;
    unsigned char* srcLow = (unsigned char*)w; w += (size_t)E;

    coarse_hist<<<NCHUNK_R, 256, 0, stream>>>(src, dst, partS, partD, E, chunkE);
    scan_chunks<<<512, 256, 0, stream>>>(partS, partD, totS, totD, NCHUNK_R);
    partition_coarse<<<NCHUNK_R, 256, 0, stream>>>(src, dst, partS, partD, totS, totD,
                                                   packD, srcLow, E, chunkE);
    fine_both<<<512, 256, 0, stream>>>(packD, totD, sorted_src, oc, norm_dst,
                                       srcLow, totS, norm_src, N);
    gemm1_kernel<<<(N + 127) / 128, 256, 0, stream>>>(X, W1, norm_src, h1, N);
    const int nblk1 = 2048;
    agg1_fused<<<nblk1, 256, 0, stream>>>(h1, sorted_src, oc, norm_dst, norm_src,
                                          b1, W2, h2, N, nblk1 * 4);
    const int nblk2 = 1536;
    agg2_kernel<<<nblk2, 256, 0, stream>>>(h2, sorted_src, oc, norm_dst, b2, out, N, nblk2 * 4);
}

// Round 20
// 164.511 us; speedup vs baseline: 1.0176x; 1.0176x over previous
//
#include <hip/hip_runtime.h>
#include <hip/hip_fp16.h>

#define FEAT1 64
#define FEAT2 16
#define NCHUNK_R 800   // radix chunks (chunkE = 1000 edges)
#define FCAP 4096      // LDS cache capacity for fine_both dst bucket

typedef _Float16 f16x8 __attribute__((ext_vector_type(8)));
typedef _Float16 f16x4 __attribute__((ext_vector_type(4)));
typedef float f32x4 __attribute__((ext_vector_type(4)));
typedef float f32x2 __attribute__((ext_vector_type(2)));

#define DPP_ADD(x, ctrl) \
    ((x) + __int_as_float(__builtin_amdgcn_update_dpp(0, __float_as_int(x), (ctrl), 0xf, 0xf, true)))

// ---------------- radix sort pipeline ----------------

__global__ __launch_bounds__(256) void coarse_hist(const int* __restrict__ src,
                                                   const int* __restrict__ dst,
                                                   int* __restrict__ partS, int* __restrict__ partD,
                                                   int E, int chunkE) {
    __shared__ int hS[256], hD[256];
    int tid = threadIdx.x, chunk = blockIdx.x;
    hS[tid] = 0; hD[tid] = 0;
    __syncthreads();
    int e0 = chunk * chunkE;
    int nq = chunkE >> 2;
    if (tid < nq) {
        int e = e0 + tid * 4;
        if (e + 3 < E) {
            int4 s4 = *(const int4*)(src + e);
            int4 d4 = *(const int4*)(dst + e);
            atomicAdd(&hS[s4.x >> 8], 1); atomicAdd(&hS[s4.y >> 8], 1);
            atomicAdd(&hS[s4.z >> 8], 1); atomicAdd(&hS[s4.w >> 8], 1);
            atomicAdd(&hD[d4.x >> 8], 1); atomicAdd(&hD[d4.y >> 8], 1);
            atomicAdd(&hD[d4.z >> 8], 1); atomicAdd(&hD[d4.w >> 8], 1);
        } else {
            for (int k = 0; k < 4 && e + k < E; k++) {
                atomicAdd(&hS[src[e + k] >> 8], 1);
                atomicAdd(&hD[dst[e + k] >> 8], 1);
            }
        }
    }
    __syncthreads();
    partS[chunk * 256 + tid] = hS[tid];
    partD[chunk * 256 + tid] = hD[tid];
}

__global__ __launch_bounds__(256) void scan_chunks(int* partS, int* partD,
                                                   int* totS, int* totD, int nchunk) {
    __shared__ int sums[256];
    int tid = threadIdx.x;
    int bin = blockIdx.x & 255;
    int* part = (blockIdx.x >> 8) ? partD : partS;
    int* tot  = (blockIdx.x >> 8) ? totD : totS;
    int v[4];
    int base = tid * 4, local = 0;
#pragma unroll
    for (int j = 0; j < 4; j++) {
        int c = base + j;
        v[j] = (c < nchunk) ? part[c * 256 + bin] : 0;
        local += v[j];
    }
    sums[tid] = local;
    __syncthreads();
    for (int off = 1; off < 256; off <<= 1) {
        int t = (tid >= off) ? sums[tid - off] : 0;
        __syncthreads();
        sums[tid] += t;
        __syncthreads();
    }
    int run = sums[tid] - local;
#pragma unroll
    for (int j = 0; j < 4; j++) {
        int c = base + j;
        if (c < nchunk) part[c * 256 + bin] = run;
        run += v[j];
    }
    if (tid == 255) tot[bin] = run;
}

__global__ __launch_bounds__(256) void partition_coarse(const int* __restrict__ src,
                                                        const int* __restrict__ dst,
                                                        const int* __restrict__ partS,
                                                        const int* __restrict__ partD,
                                                        const int* __restrict__ totS,
                                                        const int* __restrict__ totD,
                                                        unsigned int* __restrict__ packD,
                                                        unsigned char* __restrict__ srcLow,
                                                        int E, int chunkE) {
    __shared__ int curS[256], curD[256], sc[256];
    int tid = threadIdx.x, chunk = blockIdx.x;
    int v = totS[tid];
    sc[tid] = v;
    __syncthreads();
    for (int off = 1; off < 256; off <<= 1) {
        int t = (tid >= off) ? sc[tid - off] : 0;
        __syncthreads();
        sc[tid] += t;
        __syncthreads();
    }
    curS[tid] = (sc[tid] - v) + partS[chunk * 256 + tid];
    __syncthreads();
    v = totD[tid];
    sc[tid] = v;
    __syncthreads();
    for (int off = 1; off < 256; off <<= 1) {
        int t = (tid >= off) ? sc[tid - off] : 0;
        __syncthreads();
        sc[tid] += t;
        __syncthreads();
    }
    curD[tid] = (sc[tid] - v) + partD[chunk * 256 + tid];
    __syncthreads();
    int e0 = chunk * chunkE;
    int nq = chunkE >> 2;
    if (tid < nq) {
        int e = e0 + tid * 4;
        if (e + 3 < E) {
            int4 s4 = *(const int4*)(src + e);
            int4 d4 = *(const int4*)(dst + e);
            int ss[4] = {s4.x, s4.y, s4.z, s4.w};
            int dd[4] = {d4.x, d4.y, d4.z, d4.w};
#pragma unroll
            for (int k = 0; k < 4; k++) {
                int pD = atomicAdd(&curD[dd[k] >> 8], 1);
                packD[pD] = ((unsigned)(dd[k] & 255) << 16) | (unsigned)ss[k];
                int pS = atomicAdd(&curS[ss[k] >> 8], 1);
                srcLow[pS] = (unsigned char)(ss[k] & 255);
            }
        } else {
            for (int k = 0; k < 4 && e + k < E; k++) {
                int s = src[e + k], d = dst[e + k];
                int pD = atomicAdd(&curD[d >> 8], 1);
                packD[pD] = ((unsigned)(d & 255) << 16) | (unsigned)s;
                int pS = atomicAdd(&curS[s >> 8], 1);
                srcLow[pS] = (unsigned char)(s & 255);
            }
        }
    }
}

// fine stage: blocks 0..255 = dst buckets (sort into u16 sorted_src + oc int2),
// 256..511 = src buckets (norm_src)
__global__ __launch_bounds__(256) void fine_both(const unsigned int* __restrict__ packD,
                                                 const int* __restrict__ totD,
                                                 unsigned short* __restrict__ sorted_src,
                                                 int2* __restrict__ oc,
                                                 float* __restrict__ norm_dst,
                                                 const unsigned char* __restrict__ srcLow,
                                                 const int* __restrict__ totS,
                                                 float* __restrict__ norm_src, int N) {
    __shared__ int hist[256], pfx[256], cur[256];
    __shared__ unsigned int ecache[FCAP];
    int tid = threadIdx.x;
    if (blockIdx.x < 256) {
        int b = blockIdx.x;
        int tv = totD[tid];
        pfx[tid] = tv;
        __syncthreads();
        for (int off = 1; off < 256; off <<= 1) {
            int t = (tid >= off) ? pfx[tid - off] : 0;
            __syncthreads();
            pfx[tid] += t;
            __syncthreads();
        }
        int lo = pfx[b] - totD[b];
        int n = totD[b];
        __syncthreads();
        hist[tid] = 0;
        for (int i = tid; i < n; i += 256) {
            unsigned p = packD[lo + i];
            if (i < FCAP) ecache[i] = p;
            atomicAdd(&hist[p >> 16], 1);
        }
        __syncthreads();
        int v = hist[tid];
        pfx[tid] = v;
        __syncthreads();
        for (int off = 1; off < 256; off <<= 1) {
            int t = (tid >= off) ? pfx[tid - off] : 0;
            __syncthreads();
            pfx[tid] += t;
            __syncthreads();
        }
        int my = pfx[tid] - v;
        cur[tid] = lo + my;
        int node = b * 256 + tid;
        if (node < N) {
            oc[node] = make_int2(lo + my, v);
            norm_dst[node] = rsqrtf(fmaxf((float)v, 1.0f));
        }
        __syncthreads();
        for (int i = tid; i < n; i += 256) {
            unsigned p = (i < FCAP) ? ecache[i] : packD[lo + i];
            int pos = atomicAdd(&cur[p >> 16], 1);
            sorted_src[pos] = (unsigned short)(p & 0xFFFFu);
        }
    } else {
        int b = blockIdx.x - 256;
        int tv = totS[tid];
        pfx[tid] = tv;
        __syncthreads();
        for (int off = 1; off < 256; off <<= 1) {
            int t = (tid >= off) ? pfx[tid - off] : 0;
            __syncthreads();
            pfx[tid] += t;
            __syncthreads();
        }
        int lo = pfx[b] - totS[b];
        int n = totS[b];
        __syncthreads();
        hist[tid] = 0;
        __syncthreads();
        for (int i = lo + tid; i < lo + n; i += 256) atomicAdd(&hist[srcLow[i]], 1);
        __syncthreads();
        int node = b * 256 + tid;
        if (node < N) norm_src[node] = rsqrtf(fmaxf((float)hist[tid], 1.0f));
    }
}

// ---------------- MFMA GEMM layer 1 -> fp8 h1 ----------------

__global__ __launch_bounds__(256) void gemm1_kernel(const float* __restrict__ X,
                                                    const float* __restrict__ W1,
                                                    const float* __restrict__ norm_src,
                                                    unsigned char* __restrict__ h1, int N) {
    __shared__ _Float16 sWt[64 * 72];
    __shared__ float snorm[128];
    __shared__ _Float16 sTile[4][16 * 72];
    int tid = threadIdx.x;
    int row_blk = blockIdx.x * 128;
    for (int i = tid; i < 4096; i += 256) {
        int k = i >> 6, n = i & 63;
        sWt[n * 72 + k] = (_Float16)W1[i];
    }
    if (tid < 128) {
        int r = row_blk + tid;
        snorm[tid] = (r < N) ? norm_src[r] : 0.f;
    }
    __syncthreads();
    int wave = tid >> 6, lane = tid & 63;
    int m = lane & 15, quad = lane >> 4;
    f16x8 bfrag[4][2];
#pragma unroll
    for (int nt = 0; nt < 4; nt++)
#pragma unroll
        for (int kit = 0; kit < 2; kit++)
            bfrag[nt][kit] = *(const f16x8*)&sWt[(nt * 16 + m) * 72 + kit * 32 + quad * 8];
    _Float16* tile = sTile[wave];
#pragma unroll
    for (int t = 0; t < 2; t++) {
        int row0 = row_blk + wave * 32 + t * 16;
        int row = row0 + m;
        bool inb = row < N;
        f32x4 acc[4] = {{0.f,0.f,0.f,0.f},{0.f,0.f,0.f,0.f},{0.f,0.f,0.f,0.f},{0.f,0.f,0.f,0.f}};
#pragma unroll
        for (int kit = 0; kit < 2; kit++) {
            f16x8 afrag;
            if (inb) {
                const float4* xp = (const float4*)(X + (size_t)row * 64 + kit * 32 + quad * 8);
                float4 x0 = xp[0], x1 = xp[1];
                afrag[0] = (_Float16)x0.x; afrag[1] = (_Float16)x0.y;
                afrag[2] = (_Float16)x0.z; afrag[3] = (_Float16)x0.w;
                afrag[4] = (_Float16)x1.x; afrag[5] = (_Float16)x1.y;
                afrag[6] = (_Float16)x1.z; afrag[7] = (_Float16)x1.w;
            } else {
#pragma unroll
                for (int j = 0; j < 8; j++) afrag[j] = (_Float16)0.f;
            }
#pragma unroll
            for (int nt = 0; nt < 4; nt++)
                acc[nt] = __builtin_amdgcn_mfma_f32_16x16x32_f16(afrag, bfrag[nt][kit], acc[nt], 0, 0, 0);
        }
#pragma unroll
        for (int reg = 0; reg < 4; reg++) {
            int r = quad * 4 + reg;
            float nrm = snorm[wave * 32 + t * 16 + r];
#pragma unroll
            for (int nt = 0; nt < 4; nt++)
                tile[r * 72 + nt * 16 + m] = (_Float16)(acc[nt][reg] * nrm);
        }
        __syncthreads();
        int rr = lane >> 2, g = lane & 3;
        f16x8 p0 = *(const f16x8*)&tile[rr * 72 + g * 16];
        f16x8 p1 = *(const f16x8*)&tile[rr * 72 + g * 16 + 8];
        int orow = row0 + rr;
        if (orow < N) {
            int a, b;
            uint4 wv;
            a = __builtin_amdgcn_cvt_pk_fp8_f32((float)p0[0], (float)p0[1], 0, false);
            b = __builtin_amdgcn_cvt_pk_fp8_f32((float)p0[2], (float)p0[3], a, true);
            wv.x = (unsigned)b;
            a = __builtin_amdgcn_cvt_pk_fp8_f32((float)p0[4], (float)p0[5], 0, false);
            b = __builtin_amdgcn_cvt_pk_fp8_f32((float)p0[6], (float)p0[7], a, true);
            wv.y = (unsigned)b;
            a = __builtin_amdgcn_cvt_pk_fp8_f32((float)p1[0], (float)p1[1], 0, false);
            b = __builtin_amdgcn_cvt_pk_fp8_f32((float)p1[2], (float)p1[3], a, true);
            wv.z = (unsigned)b;
            a = __builtin_amdgcn_cvt_pk_fp8_f32((float)p1[4], (float)p1[5], 0, false);
            b = __builtin_amdgcn_cvt_pk_fp8_f32((float)p1[6], (float)p1[7], a, true);
            wv.w = (unsigned)b;
            *(uint4*)(h1 + (size_t)orow * 64 + g * 16) = wv;
        }
        __syncthreads();
    }
}

// ---------------- fused agg1 (fp8 gather, packed accumulate) ----------------

__global__ __launch_bounds__(256) void agg1_fused(const unsigned char* __restrict__ h1,
                                                  const unsigned short* __restrict__ sorted_src,
                                                  const int2* __restrict__ oc,
                                                  const float* __restrict__ norm_dst,
                                                  const float* __restrict__ norm_src,
                                                  const float* __restrict__ b1,
                                                  const float* __restrict__ W2,
                                                  __half* __restrict__ h2, int N, int nwaves) {
    int tid = threadIdx.x;
    int wave = tid >> 6, lane = tid & 63;
    int e_off = lane >> 3;   // 0..7
    int fg = lane & 7;       // feats 8fg..8fg+7
    float w2r[8][2], b1r[8];
#pragma unroll
    for (int k = 0; k < 8; k++) {
        float2 t = *(const float2*)(W2 + (size_t)(fg * 8 + k) * 16 + 2 * e_off);
        w2r[k][0] = t.x; w2r[k][1] = t.y;
        b1r[k] = b1[fg * 8 + k];
    }
    for (int row = blockIdx.x * 4 + wave; row < N; row += nwaves) {
        int2 sc = oc[row];
        int start = sc.x, c = sc.y;
        float nd = norm_dst[row];
        f32x2 acc2[4] = {{0.f,0.f},{0.f,0.f},{0.f,0.f},{0.f,0.f}};
        for (int j = 0; j < c; j += 8) {
            int je = j + e_off;
            if (je < c) {
                int s = sorted_src[start + je];
                uint2 wv = *(const uint2*)(h1 + (size_t)s * 64 + fg * 8);
                acc2[0] += __builtin_amdgcn_cvt_pk_f32_fp8((int)wv.x, false);
                acc2[1] += __builtin_amdgcn_cvt_pk_f32_fp8((int)wv.x, true);
                acc2[2] += __builtin_amdgcn_cvt_pk_f32_fp8((int)wv.y, false);
                acc2[3] += __builtin_amdgcn_cvt_pk_f32_fp8((int)wv.y, true);
            }
        }
        float acc[8] = {acc2[0][0], acc2[0][1], acc2[1][0], acc2[1][1],
                        acc2[2][0], acc2[2][1], acc2[3][0], acc2[3][1]};
#pragma unroll
        for (int k = 0; k < 8; k++) acc[k] = DPP_ADD(acc[k], 0x128);  // xor8
#pragma unroll
        for (int m = 16; m <= 32; m <<= 1)
#pragma unroll
            for (int k = 0; k < 8; k++) acc[k] += __shfl_xor(acc[k], m);
        float p0 = 0.f, p1 = 0.f;
#pragma unroll
        for (int k = 0; k < 8; k++) {
            float t = fmaxf(acc[k] * nd + b1r[k], 0.f);
            p0 += t * w2r[k][0];
            p1 += t * w2r[k][1];
        }
        p0 = DPP_ADD(p0, 0xB1);
        p1 = DPP_ADD(p1, 0xB1);
        p0 = DPP_ADD(p0, 0x4E);
        p1 = DPP_ADD(p1, 0x4E);
        p0 += __shfl_xor(p0, 4);
        p1 += __shfl_xor(p1, 4);
        if (fg == 0) {
            float ns = norm_src[row];
            ((__half2*)((_Float16*)h2 + (size_t)row * 16))[e_off] =
                __floats2half2_rn(p0 * ns, p1 * ns);
        }
    }
}

// ---------------- layer-2 aggregation + epilogue (grid-stride, packed) ----------------

__global__ __launch_bounds__(256) void agg2_kernel(const __half* __restrict__ h2,
                                                   const unsigned short* __restrict__ sorted_src,
                                                   const int2* __restrict__ oc,
                                                   const float* __restrict__ norm_dst,
                                                   const float* __restrict__ b2,
                                                   float* __restrict__ out, int N, int nwaves) {
    int tid = threadIdx.x;
    int wave = tid >> 6, lane = tid & 63;
    int e_off = lane >> 2;   // 0..15
    int fg = lane & 3;       // feats 4fg..4fg+3
    float b2r[4];
#pragma unroll
    for (int k = 0; k < 4; k++) b2r[k] = b2[fg * 4 + k];
    const _Float16* h2p = (const _Float16*)h2;
    for (int row = blockIdx.x * 4 + wave; row < N; row += nwaves) {
        int2 sc = oc[row];
        int start = sc.x, c = sc.y;
        f32x2 acc2[2] = {{0.f,0.f},{0.f,0.f}};
        for (int j = 0; j < c; j += 16) {
            int je = j + e_off;
            if (je < c) {
                int s = sorted_src[start + je];
                f16x4 v = *(const f16x4*)(h2p + (size_t)s * 16 + fg * 4);
                f32x2 f0 = {(float)v[0], (float)v[1]};
                f32x2 f1 = {(float)v[2], (float)v[3]};
                acc2[0] += f0;
                acc2[1] += f1;
            }
        }
        float acc[4] = {acc2[0][0], acc2[0][1], acc2[1][0], acc2[1][1]};
#pragma unroll
        for (int k = 0; k < 4; k++) acc[k] += __shfl_xor(acc[k], 4);
#pragma unroll
        for (int k = 0; k < 4; k++) acc[k] = DPP_ADD(acc[k], 0x128);  // xor8
#pragma unroll
        for (int m = 16; m <= 32; m <<= 1)
#pragma unroll
            for (int k = 0; k < 4; k++) acc[k] += __shfl_xor(acc[k], m);
        if (e_off == 0) {
            float nd = norm_dst[row];
            float4 o;
            o.x = acc[0] * nd + b2r[0];
            o.y = acc[1] * nd + b2r[1];
            o.z = acc[2] * nd + b2r[2];
            o.w = acc[3] * nd + b2r[3];
            ((float4*)(out + (size_t)row * 16))[fg] = o;
        }
    }
}

extern "C" void kernel_launch(void* const* d_in, const int* in_sizes, int n_in,
                              void* d_out, int out_size, void* d_ws, size_t ws_size,
                              hipStream_t stream) {
    const float* X  = (const float*)d_in[0];
    const int* src  = (const int*)d_in[1];
    const int* dst  = (const int*)d_in[2];
    const float* W1 = (const float*)d_in[3];
    const float* b1 = (const float*)d_in[4];
    const float* W2 = (const float*)d_in[5];
    const float* b2 = (const float*)d_in[6];
    float* out = (float*)d_out;

    const int N = in_sizes[0] / FEAT1;  // 50000
    const int E = in_sizes[1];          // 800000
    const int chunkE = (E + NCHUNK_R - 1) / NCHUNK_R;  // 1000

    char* w = (char*)d_ws;
    int* partS = (int*)w;        w += (size_t)NCHUNK_R * 256 * 4;
    int* partD = (int*)w;        w += (size_t)NCHUNK_R * 256 * 4;
    int* totS  = (int*)w;        w += 256 * 4;
    int* totD  = (int*)w;        w += 256 * 4;
    unsigned int* packD = (unsigned int*)w; w += (size_t)E * 4;
    unsigned short* sorted_src = (unsigned short*)w; w += (size_t)E * 2;
    w = (char*)(((size_t)w + 7) & ~(size_t)7);
    int2* oc = (int2*)w;         w += (size_t)N * 8;
    float* norm_src = (float*)w; w += (size_t)N * 4;
    float* norm_dst = (float*)w; w += (size_t)N * 4;
    unsigned char* h1 = (unsigned char*)w; w += (size_t)N * 64;
    __half* h2 = (__half*)w;     w += (size_t)N * 16 * 2;
    unsigned char* srcLow = (unsigned char*)w; w += (size_t)E;

    coarse_hist<<<NCHUNK_R, 256, 0, stream>>>(src, dst, partS, partD, E, chunkE);
    scan_chunks<<<512, 256, 0, stream>>>(partS, partD, totS, totD, NCHUNK_R);
    partition_coarse<<<NCHUNK_R, 256, 0, stream>>>(src, dst, partS, partD, totS, totD,
                                                   packD, srcLow, E, chunkE);
    fine_both<<<512, 256, 0, stream>>>(packD, totD, sorted_src, oc, norm_dst,
                                       srcLow, totS, norm_src, N);
    gemm1_kernel<<<(N + 127) / 128, 256, 0, stream>>>(X, W1, norm_src, h1, N);
    const int nblk1 = 4096;
    agg1_fused<<<nblk1, 256, 0, stream>>>(h1, sorted_src, oc, norm_dst, norm_src,
                                          b1, W2, h2, N, nblk1 * 4);
    const int nblk2 = 3072;
    agg2_kernel<<<nblk2, 256, 0, stream>>>(h2, sorted_src, oc, norm_dst, b2, out, N, nblk2 * 4);
}